// Round 4
// baseline (1119.386 us; speedup 1.0000x reference)
//
#include <hip/hip_runtime.h>
#include <cmath>

#define HH 512
#define WW 512
#define NB 8
#define CIN 4
#define C2 32
#define C3 16
#define CF 8
#define HW (HH*WW)      /* 262144 */
#define NPIX (NB*HW)    /* 2097152 */

__device__ __forceinline__ float lrelu_f(float v){ return v < 0.f ? 0.2f*v : v; }
__device__ __forceinline__ int reflect_i(int i){ int r = i < 0 ? -i : i; return r >= HH ? 2*HH - 2 - r : r; }

// ---------------------------------------------------------------------------
// Fused conv1(4->32)+lrelu+conv2(32->16)+lrelu. Tile: 64 cols x 8 rows of f2,
// all 16 oc. Phase A: compute 10x66x32 f1 patch into LDS (1.25x conv1
// recompute). Phase B: conv2 from LDS; thread = 4px x 8oc x (8 rows x 16
// colgroups x 2 ocgroups = 256 thr). Weights via broadcast ds_read_b128
// (w2 pre-transposed [ocg][ci][oc][tap] = 72 contiguous floats per (ocg,ci)).
// ---------------------------------------------------------------------------
__global__ __launch_bounds__(256) void k_fused12(const float* __restrict__ x,
                                                 const float* __restrict__ w1,
                                                 const float* __restrict__ b1,
                                                 const float* __restrict__ w2,
                                                 const float* __restrict__ b2,
                                                 float* __restrict__ f2)
{
    __shared__ float f1t[10*32*68];   // [rr10][ch32][cc68(66 used)]   87.0 KB
    __shared__ float xt [4*12*68];    // [ci4][xr12][xx68]             13.1 KB
    __shared__ float w2s[2*32*72];    // [ocg2][ci32][ocl8*tap9]       18.4 KB
    __shared__ float w1l[32*4*9];     //                                4.6 KB
    __shared__ float b1l[32];
    __shared__ float b2l[16];

    int bx = blockIdx.x;
    int s  = bx & 7;            // col strip (64)
    int d  = (bx >> 3) & 63;    // row band (8)
    int b  = bx >> 9;           // batch
    int r0 = d*8;
    int c0 = s*64;
    int tid = threadIdx.x;

    // --- stage weights & x tile ---
    for (int i = tid; i < 1152; i += 256) w1l[i] = w1[i];
    for (int i = tid; i < 4608; i += 256){
        int ocg = i / 2304, r = i - ocg*2304;
        int ci  = r / 72;   r -= ci*72;
        int ocl = r / 9;    int tap = r - ocl*9;
        w2s[i] = w2[((ocg*8 + ocl)*C2 + ci)*9 + tap];
    }
    if (tid < 32) b1l[tid] = b1[tid];
    if (tid < 16) b2l[tid] = b2[tid];
    for (int i = tid; i < 4*12*68; i += 256){
        int ci = i / (12*68), r = i - ci*(12*68);
        int xr = r / 68, xx = r - xr*68;
        int ar = r0 - 2 + xr, ac = c0 - 2 + xx;
        float v = 0.f;
        if ((unsigned)ar < (unsigned)HH && (unsigned)ac < (unsigned)WW)
            v = x[((size_t)(b*CIN + ci)*HH + ar)*WW + ac];
        xt[i] = v;
    }
    __syncthreads();

    // --- Phase A: f1 patch (rows r0-1..r0+8, cols c0-1..c0+64) ---
    {
        int ch = tid >> 3;          // 0..31
        int g  = tid & 7;           // 9 cols each
        float wr1[36];
        #pragma unroll
        for (int t = 0; t < 36; t++) wr1[t] = w1l[ch*36 + t];
        float bz = b1l[ch];

        #pragma unroll 1
        for (int rr = 0; rr < 10; rr++){
            int fr = r0 - 1 + rr;
            bool frok = (unsigned)fr < (unsigned)HH;
            float sums[9];
            #pragma unroll
            for (int k = 0; k < 9; k++) sums[k] = bz;
            if (frok){
                #pragma unroll
                for (int ci = 0; ci < 4; ci++){
                    float xv[3][11];
                    #pragma unroll
                    for (int dy = 0; dy < 3; dy++)
                        #pragma unroll
                        for (int xx = 0; xx < 11; xx++)
                            xv[dy][xx] = xt[(ci*12 + rr + dy)*68 + g*9 + xx];
                    #pragma unroll
                    for (int k = 0; k < 9; k++)
                        #pragma unroll
                        for (int dy = 0; dy < 3; dy++)
                            #pragma unroll
                            for (int dx = 0; dx < 3; dx++)
                                sums[k] = fmaf(xv[dy][k+dx], wr1[ci*9 + dy*3 + dx], sums[k]);
                }
            }
            #pragma unroll
            for (int k = 0; k < 9; k++){
                int cc = g*9 + k;
                if (cc < 66){
                    int fc = c0 - 1 + cc;
                    float v = (frok && (unsigned)fc < (unsigned)WW) ? lrelu_f(sums[k]) : 0.f;
                    f1t[(rr*32 + ch)*68 + cc] = v;
                }
            }
        }
    }
    __syncthreads();

    // --- Phase B: conv2 from LDS ---
    {
        int row = tid >> 5;         // 0..7
        int rem = tid & 31;
        int ocg = rem >> 4;         // 0..1
        int cg  = rem & 15;         // cols 4*cg
        float acc[8][4];
        #pragma unroll
        for (int oc = 0; oc < 8; oc++){
            float bv = b2l[ocg*8 + oc];
            #pragma unroll
            for (int p = 0; p < 4; p++) acc[oc][p] = bv;
        }
        #pragma unroll 1
        for (int ci = 0; ci < 32; ci++){
            float wv[72];
            const float* wp = &w2s[(ocg*32 + ci)*72];
            #pragma unroll
            for (int t = 0; t < 72; t++) wv[t] = wp[t];
            float fw[3][6];
            #pragma unroll
            for (int dr = 0; dr < 3; dr++)
                #pragma unroll
                for (int e = 0; e < 6; e++)
                    fw[dr][e] = f1t[((row+dr)*32 + ci)*68 + 4*cg + e];
            #pragma unroll
            for (int oc = 0; oc < 8; oc++)
                #pragma unroll
                for (int dy = 0; dy < 3; dy++)
                    #pragma unroll
                    for (int dx = 0; dx < 3; dx++){
                        float wvv = wv[oc*9 + dy*3 + dx];
                        #pragma unroll
                        for (int p = 0; p < 4; p++)
                            acc[oc][p] = fmaf(fw[dy][dx+p], wvv, acc[oc][p]);
                    }
        }
        int r = r0 + row, c = c0 + 4*cg;
        #pragma unroll
        for (int oc = 0; oc < 8; oc++){
            float4 o;
            o.x = lrelu_f(acc[oc][0]); o.y = lrelu_f(acc[oc][1]);
            o.z = lrelu_f(acc[oc][2]); o.w = lrelu_f(acc[oc][3]);
            *(float4*)(f2 + ((size_t)(b*C3 + ocg*8 + oc)*HH + r)*WW + c) = o;
        }
    }
}

// ---------------------------------------------------------------------------
// Conv 3x3 (zero pad=1). Thread = 4 px x 8 oc. Used for conv3 (16->8).
// ---------------------------------------------------------------------------
template<int Ci, int Co, bool LRELU>
__global__ __launch_bounds__(256) void k_conv(const float* __restrict__ in,
                                              const float* __restrict__ wgt,
                                              const float* __restrict__ bias,
                                              float* __restrict__ outp)
{
    constexpr int NG = Co/8;
    __shared__ float wl[Co*Ci*9];
    __shared__ float bl[Co];
    for (int i = threadIdx.x; i < Co*Ci*9; i += 256) wl[i] = wgt[i];
    if (threadIdx.x < Co) bl[threadIdx.x] = bias[threadIdx.x];
    __syncthreads();

    int t   = blockIdx.x*256 + threadIdx.x;
    int pix = t & 65535;
    int r   = t >> 16;
    int cg  = r % NG;
    int b   = r / NG;
    int h   = pix >> 7;
    int w0  = (pix & 127) << 2;
    int co0 = cg*8;
    const float* inb = in + (size_t)b*Ci*HW;

    float acc[8][4];
    #pragma unroll
    for (int j=0;j<8;j++){
        float bv = bl[co0+j];
        #pragma unroll
        for (int p=0;p<4;p++) acc[j][p] = bv;
    }

    #pragma unroll 2
    for (int ci=0; ci<Ci; ci++){
        float v[3][6];
        const float* inc = inb + (size_t)ci*HW;
        #pragma unroll
        for (int dy=0;dy<3;dy++){
            int hh = h + dy - 1;
            int hc = hh < 0 ? 0 : (hh > HH-1 ? HH-1 : hh);
            bool hok = (unsigned)hh < (unsigned)HH;
            #pragma unroll
            for (int dx=0;dx<6;dx++){
                int wx = w0 + dx - 1;
                int wc = wx < 0 ? 0 : (wx > WW-1 ? WW-1 : wx);
                float val = inc[hc*WW + wc];
                v[dy][dx] = (hok && (unsigned)wx < (unsigned)WW) ? val : 0.f;
            }
        }
        #pragma unroll
        for (int j=0;j<8;j++){
            const float* wr = &wl[((co0+j)*Ci + ci)*9];
            #pragma unroll
            for (int dy=0;dy<3;dy++){
                #pragma unroll
                for (int dx=0;dx<3;dx++){
                    float wv = wr[dy*3+dx];
                    #pragma unroll
                    for (int p=0;p<4;p++)
                        acc[j][p] = fmaf(v[dy][dx+p], wv, acc[j][p]);
                }
            }
        }
    }

    float* ob = outp + (size_t)b*Co*HW;
    #pragma unroll
    for (int j=0;j<8;j++){
        float4 o;
        o.x = LRELU ? lrelu_f(acc[j][0]) : acc[j][0];
        o.y = LRELU ? lrelu_f(acc[j][1]) : acc[j][1];
        o.z = LRELU ? lrelu_f(acc[j][2]) : acc[j][2];
        o.w = LRELU ? lrelu_f(acc[j][3]) : acc[j][3];
        *(float4*)(ob + (size_t)(co0+j)*HW + h*WW + w0) = o;
    }
}

// ---------------------------------------------------------------------------
// Vertical box pass: thread walks a column chunk with register sliding window.
// ---------------------------------------------------------------------------
template<int WS>
__global__ __launch_bounds__(256) void k_vbox(const float* __restrict__ f,
                                              float* __restrict__ vs,
                                              float* __restrict__ vq)
{
    constexpr int P = WS/2;
    constexpr int CH = 64;
    int bid   = blockIdx.x;
    int wb    = bid & 1;
    int hc    = (bid >> 1) & 7;
    int plane = bid >> 4;
    int w     = wb*256 + threadIdx.x;
    int h0    = hc*CH;
    const float* base = f  + (size_t)plane*HW + w;
    float*       os   = vs + (size_t)plane*HW + w;
    float*       oq   = vq + (size_t)plane*HW + w;

    float s = 0.f, q = 0.f;
    #pragma unroll
    for (int dy = -P; dy <= P; dy++){
        float v = base[(size_t)reflect_i(h0+dy)*WW];
        s += v; q = fmaf(v, v, q);
    }
    #pragma unroll 4
    for (int h = h0; h < h0+CH; h++){
        os[(size_t)h*WW] = s;
        oq[(size_t)h*WW] = q;
        float e = base[(size_t)reflect_i(h+1+P)*WW];
        float l = base[(size_t)reflect_i(h-P)*WW];
        s += e - l;
        q = fmaf(e, e, q);
        q = fmaf(-l, l, q);
    }
}

// ---------------------------------------------------------------------------
// Horizontal box pass + var/sqrt/channel-sum/pow0.8 + fused accumulate.
// ---------------------------------------------------------------------------
__device__ __forceinline__ int swz_i(int j){ return j + (j >> 4); }

template<int WS>
__global__ __launch_bounds__(256) void k_hbox(const float* __restrict__ vs,
                                              const float* __restrict__ vq,
                                              float* __restrict__ fused,
                                              const float* __restrict__ fwv, int sidx)
{
    constexpr int P   = WS/2;
    constexpr int L   = WW + 2*P;
    constexpr int SWL = L + (L >> 4) + 2;
    constexpr float inv = 1.f/((float)WS*(float)WS);
    __shared__ float sv[CF*SWL];
    __shared__ float sq[CF*SWL];

    int bid = blockIdx.x;
    int row = bid & (HH-1);
    int bb  = bid >> 9;
    const float* vsb = vs + ((size_t)bb*CF*HH + row)*WW;
    const float* vqb = vq + ((size_t)bb*CF*HH + row)*WW;

    for (int i = threadIdx.x; i < CF*L; i += 256){
        int c = i / L, j = i - c*L;
        int s = j - P; s = s < 0 ? -s : (s > WW-1 ? 2*WW-2 - s : s);
        sv[c*SWL + swz_i(j)] = vsb[(size_t)c*HW + s];
        sq[c*SWL + swz_i(j)] = vqb[(size_t)c*HW + s];
    }
    __syncthreads();

    int c = threadIdx.x >> 5;
    int g = threadIdx.x & 31;
    const float* pv = sv + c*SWL;
    const float* pq = sq + c*SWL;
    int bofs = 17*g;

    float S = 0.f, Q = 0.f;
    #pragma unroll
    for (int k = 0; k < WS; k++){
        S += pv[bofs + k + (k>>4)];
        Q += pq[bofs + k + (k>>4)];
    }
    float res[16];
    #pragma unroll
    for (int k = 0; k < 16; k++){
        float m  = S*inv;
        float m2 = Q*inv;
        float var = fmaxf(fmaf(-m, m, m2), 1e-6f);
        res[k] = sqrtf(var);
        if (k < 15){
            S += pv[bofs + (k+WS) + ((k+WS)>>4)] - pv[bofs + k + (k>>4)];
            Q += pq[bofs + (k+WS) + ((k+WS)>>4)] - pq[bofs + k + (k>>4)];
        }
    }
    __syncthreads();
    #pragma unroll
    for (int k = 0; k < 16; k++) sv[c*SWL + bofs + k + (k>>4)] = res[k];
    __syncthreads();

    float fwb = fwv[sidx];
    #pragma unroll
    for (int half = 0; half < 2; half++){
        int col = threadIdx.x + half*256;
        float a = 0.f;
        #pragma unroll
        for (int cc = 0; cc < CF; cc++) a += sv[cc*SWL + swz_i(col)];
        float val = powf(a*0.125f, 0.8f);
        fused[((size_t)bb*HH + row)*WW + col] += fwb*val;
    }
}

// ---------------------------------------------------------------------------
// Exact quantiles: 3-level radix (8/8/16 bits), LDS-privatized hot levels.
// ---------------------------------------------------------------------------
__global__ void k_h8(const float* __restrict__ fused, const float* __restrict__ fb,
                     unsigned* __restrict__ hist8)
{
    __shared__ unsigned lh[256];
    lh[threadIdx.x] = 0;
    __syncthreads();
    float fbv = fb[0];
    int i = blockIdx.x*256 + threadIdx.x;
    int stride = gridDim.x*256;
    for (; i < NPIX; i += stride){
        float v = fmaxf(fused[i] + fbv, 0.f);
        atomicAdd(&lh[__float_as_uint(v) >> 24], 1u);
    }
    __syncthreads();
    if (lh[threadIdx.x]) atomicAdd(&hist8[threadIdx.x], lh[threadIdx.x]);
}

__global__ void k_scan8(const unsigned* __restrict__ hist8,
                        int* __restrict__ cand8, int* __restrict__ rank8)
{
    if (threadIdx.x == 0){
        const unsigned RK[4] = {524287u, 524288u, 1572863u, 1572864u};
        unsigned cum = 0; int qi = 0;
        for (int b = 0; b < 256 && qi < 4; b++){
            unsigned cnt = hist8[b];
            while (qi < 4 && RK[qi] < cum + cnt){
                cand8[qi] = b; rank8[qi] = (int)(RK[qi] - cum); qi++;
            }
            cum += cnt;
        }
    }
}

__global__ void k_h8b(const float* __restrict__ fused, const float* __restrict__ fb,
                      const int* __restrict__ cand8, unsigned* __restrict__ hist8b)
{
    __shared__ unsigned lh[1024];
    for (int i = threadIdx.x; i < 1024; i += 256) lh[i] = 0;
    __syncthreads();
    float fbv = fb[0];
    int c0 = cand8[0], c1 = cand8[1], c2 = cand8[2], c3 = cand8[3];
    bool d1 = (c1 != c0);
    bool d2 = (c2 != c0) && (c2 != c1);
    bool d3 = (c3 != c0) && (c3 != c1) && (c3 != c2);
    int i = blockIdx.x*256 + threadIdx.x;
    int stride = gridDim.x*256;
    for (; i < NPIX; i += stride){
        unsigned u = __float_as_uint(fmaxf(fused[i] + fbv, 0.f));
        int hi = (int)(u >> 24);
        unsigned mid = (u >> 16) & 0xffu;
        if (hi == c0)       atomicAdd(&lh[mid],       1u);
        if (d1 && hi == c1) atomicAdd(&lh[256u+mid],  1u);
        if (d2 && hi == c2) atomicAdd(&lh[512u+mid],  1u);
        if (d3 && hi == c3) atomicAdd(&lh[768u+mid],  1u);
    }
    __syncthreads();
    for (int i = threadIdx.x; i < 1024; i += 256)
        if (lh[i]) atomicAdd(&hist8b[i], lh[i]);
}

__global__ void k_scan8b(const unsigned* __restrict__ hist8b,
                         const int* __restrict__ cand8, const int* __restrict__ rank8,
                         int* __restrict__ cand16, int* __restrict__ rank16)
{
    int qi = threadIdx.x;
    if (qi < 4){
        int slot = qi;
        for (int j = 0; j < qi; j++) if (cand8[j] == cand8[qi]){ slot = j; break; }
        const unsigned* h = hist8b + slot*256;
        unsigned k = (unsigned)rank8[qi], cum = 0;
        for (int b = 0; b < 256; b++){
            unsigned cnt = h[b];
            if (cnt && k >= cum && k < cum + cnt){
                cand16[qi] = (cand8[qi] << 8) | b;
                rank16[qi] = (int)(k - cum);
            }
            cum += cnt;
        }
    }
}

__global__ void k_h16(const float* __restrict__ fused, const float* __restrict__ fb,
                      const int* __restrict__ cand16, unsigned* __restrict__ histlo)
{
    float fbv = fb[0];
    int c0 = cand16[0], c1 = cand16[1], c2 = cand16[2], c3 = cand16[3];
    bool d1 = (c1 != c0);
    bool d2 = (c2 != c0) && (c2 != c1);
    bool d3 = (c3 != c0) && (c3 != c1) && (c3 != c2);
    int i = blockIdx.x*256 + threadIdx.x;
    int stride = gridDim.x*256;
    for (; i < NPIX; i += stride){
        unsigned u = __float_as_uint(fmaxf(fused[i] + fbv, 0.f));
        int hi = (int)(u >> 16);
        unsigned lo = u & 0xffffu;
        if (hi == c0)       atomicAdd(&histlo[lo],           1u);
        if (d1 && hi == c1) atomicAdd(&histlo[65536u + lo],  1u);
        if (d2 && hi == c2) atomicAdd(&histlo[131072u + lo], 1u);
        if (d3 && hi == c3) atomicAdd(&histlo[196608u + lo], 1u);
    }
}

__global__ void k_scan16(const unsigned* __restrict__ histlo,
                         const int* __restrict__ cand16, const int* __restrict__ rank16,
                         float* __restrict__ ostat)
{
    int qi = blockIdx.x;
    int slot = qi;
    for (int j = 0; j < qi; j++) if (cand16[j] == cand16[qi]){ slot = j; break; }
    const unsigned* hist = histlo + (size_t)slot*65536;
    __shared__ unsigned csum[256];
    __shared__ unsigned cbase[256];
    int t = threadIdx.x;
    unsigned s = 0;
    for (int i = 0; i < 256; i++) s += hist[t*256 + i];
    csum[t] = s;
    __syncthreads();
    if (t == 0){ unsigned run = 0; for (int i = 0; i < 256; i++){ cbase[i] = run; run += csum[i]; } }
    __syncthreads();
    unsigned k = (unsigned)rank16[qi];
    unsigned cum = cbase[t];
    for (int i = 0; i < 256; i++){
        unsigned cnt = hist[t*256 + i];
        if (cnt && k >= cum && k < cum + cnt)
            ostat[qi] = __uint_as_float(((unsigned)cand16[qi] << 16) | (unsigned)(t*256 + i));
        cum += cnt;
    }
}

// ---------------------------------------------------------------------------
// Global per-(b,c) std of x, ddof=1, double partial sums (deterministic).
// ---------------------------------------------------------------------------
__global__ void k_gstd_part(const float* __restrict__ x, double* __restrict__ part)
{
    int bid = blockIdx.x;
    int plane = bid >> 3, chunk = bid & 7;
    const float4* p4 = (const float4*)(x + (size_t)plane*HW + (size_t)chunk*32768);
    int t = threadIdx.x;
    double s=0.0, s2=0.0;
    for (int k=0;k<32;k++){
        float4 v = p4[k*256 + t];
        s  += (double)v.x + (double)v.y + (double)v.z + (double)v.w;
        s2 += (double)v.x*v.x + (double)v.y*v.y + (double)v.z*v.z + (double)v.w*v.w;
    }
    __shared__ double rs[256], rq[256];
    rs[t]=s; rq[t]=s2; __syncthreads();
    for (int off=128; off>0; off>>=1){
        if (t<off){ rs[t]+=rs[t+off]; rq[t]+=rq[t+off]; }
        __syncthreads();
    }
    if (t==0){ part[bid*2]=rs[0]; part[bid*2+1]=rq[0]; }
}

__global__ void k_gstd_final(const double* __restrict__ part, float* __restrict__ gstd)
{
    int t = threadIdx.x;
    if (t < 32){
        double s=0.0, s2=0.0;
        for (int j=0;j<8;j++){ s += part[(t*8+j)*2]; s2 += part[(t*8+j)*2+1]; }
        const double N = 262144.0;
        double var = (s2 - s*s/N) / (N - 1.0);
        gstd[t] = (float)sqrt(var < 0.0 ? 0.0 : var);
    }
}

__global__ void k_finalize(const float* __restrict__ ostat, const float* __restrict__ gstd,
                           const float* __restrict__ cwin, float* __restrict__ lov, float* __restrict__ hiv)
{
    int t = threadIdx.x;
    if (t < 32){
        float q25 = ostat[0] + 0.75f*(ostat[1]-ostat[0]);
        float q75 = ostat[2] + 0.25f*(ostat[3]-ostat[2]);
        float iqr = q75 - q25;
        float lo_b = q25 - 0.5f*iqr, hi_b = q75 + 0.5f*iqr;
        int c = t & 3;
        float m = fmaxf(fmaxf(cwin[0],cwin[1]), fmaxf(cwin[2],cwin[3]));
        float e0 = expf(cwin[0]-m), e1 = expf(cwin[1]-m), e2 = expf(cwin[2]-m), e3 = expf(cwin[3]-m);
        float smc = expf(cwin[c]-m) / (e0+e1+e2+e3);
        float g  = gstd[t];
        float gf = fminf(fmaxf(g*5.f, 0.5f), 2.f);
        float cf = fminf(fmaxf(smc*g*2.f, 0.8f), 1.2f);
        lov[t] = lo_b*gf*cf;
        hiv[t] = hi_b*gf*cf;
    }
}

__global__ void k_mask(const float* __restrict__ fused_in, const float* __restrict__ fb,
                       const float* __restrict__ lov, const float* __restrict__ hiv,
                       float* __restrict__ outp)
{
    int i = blockIdx.x*256 + threadIdx.x;
    float F = fmaxf(fused_in[i] + fb[0], 0.f);
    int b = i >> 18;
    float o = 0.f;
    #pragma unroll
    for (int c=0;c<4;c++){
        float lo = lov[b*4+c], hi = hiv[b*4+c];
        float n = (F - lo) / (hi - lo);
        n = fminf(fmaxf(n, 0.f), 1.f);
        o += 1.f/(1.f + expf(3.f - 6.f*n));
    }
    outp[i] = 0.25f * o;
}

// ---------------------------------------------------------------------------
extern "C" void kernel_launch(void* const* d_in, const int* in_sizes, int n_in,
                              void* d_out, int out_size, void* d_ws, size_t ws_size,
                              hipStream_t stream)
{
    const float* x  = (const float*)d_in[0];
    const float* w1 = (const float*)d_in[1];
    const float* b1 = (const float*)d_in[2];
    const float* w2 = (const float*)d_in[3];
    const float* b2 = (const float*)d_in[4];
    const float* w3 = (const float*)d_in[5];
    const float* b3 = (const float*)d_in[6];
    const float* fw = (const float*)d_in[7];
    const float* fb = (const float*)d_in[8];
    const float* cw = (const float*)d_in[9];
    float* out = (float*)d_out;
    char* ws = (char*)d_ws;

    size_t off = 0;
    auto take = [&](size_t bytes)->size_t{ size_t o = off; off += (bytes + 255) & ~(size_t)255; return o; };
    size_t o_f      = take((size_t)NB*CF*HW*4);     // conv3 output (64 MB)
    size_t o_h8     = take(256*4);
    size_t o_h8b    = take(1024*4);
    size_t o_histlo = take((size_t)4*65536*4);
    size_t o_c8     = take(4*4);
    size_t o_r8     = take(4*4);
    size_t o_c16    = take(4*4);
    size_t o_r16    = take(4*4);
    size_t o_os     = take(4*4);
    size_t o_part   = take(512*8);
    size_t o_gs     = take(32*4);
    size_t o_lo     = take(32*4);
    size_t o_hi     = take(32*4);
    // 128 MB region: f2 (full batch) during convs, then vs+vq during boxes
    size_t o_R      = take((size_t)NB*C3*HW*4);

    float*    fbuf   = (float*)(ws + o_f);
    float*    f2buf  = (float*)(ws + o_R);
    float*    vsb    = (float*)(ws + o_R);
    float*    vqb    = vsb + (size_t)NB*CF*HW;
    unsigned* hist8  = (unsigned*)(ws + o_h8);
    unsigned* hist8b = (unsigned*)(ws + o_h8b);
    unsigned* histlo = (unsigned*)(ws + o_histlo);
    int*      c8     = (int*)(ws + o_c8);
    int*      r8     = (int*)(ws + o_r8);
    int*      c16    = (int*)(ws + o_c16);
    int*      r16    = (int*)(ws + o_r16);
    float*    osv    = (float*)(ws + o_os);
    double*   part   = (double*)(ws + o_part);
    float*    gs     = (float*)(ws + o_gs);
    float*    lov    = (float*)(ws + o_lo);
    float*    hiv    = (float*)(ws + o_hi);

    // --- conv stack: fused conv1+conv2, then conv3, all full-batch ---
    k_fused12<<<NB*8*64, 256, 0, stream>>>(x, w1, b1, w2, b2, f2buf);
    k_conv<C3, CF, false><<<NB*256, 256, 0, stream>>>(f2buf, w3, b3, fbuf);

    // --- global stds (independent of conv chain) ---
    k_gstd_part<<<256,256,0,stream>>>(x, part);
    k_gstd_final<<<1,256,0,stream>>>(part, gs);

    // --- multi-scale std maps (f2 region is dead -> vs/vq alias it) ---
    hipMemsetAsync(out, 0, (size_t)NPIX*4, stream);
    const int vgrid = NB*CF*16, hgrid = NB*512;
    k_vbox<11><<<vgrid,256,0,stream>>>(fbuf, vsb, vqb);
    k_hbox<11><<<hgrid,256,0,stream>>>(vsb, vqb, out, fw, 0);
    k_vbox<25><<<vgrid,256,0,stream>>>(fbuf, vsb, vqb);
    k_hbox<25><<<hgrid,256,0,stream>>>(vsb, vqb, out, fw, 1);
    k_vbox<49><<<vgrid,256,0,stream>>>(fbuf, vsb, vqb);
    k_hbox<49><<<hgrid,256,0,stream>>>(vsb, vqb, out, fw, 2);

    // --- exact quantiles ---
    hipMemsetAsync(hist8,  0, 256*4,  stream);
    hipMemsetAsync(hist8b, 0, 1024*4, stream);
    hipMemsetAsync(histlo, 0, (size_t)4*65536*4, stream);
    k_h8    <<<2048,256,0,stream>>>(out, fb, hist8);
    k_scan8 <<<1,64,0,stream>>>(hist8, c8, r8);
    k_h8b   <<<2048,256,0,stream>>>(out, fb, c8, hist8b);
    k_scan8b<<<1,64,0,stream>>>(hist8b, c8, r8, c16, r16);
    k_h16   <<<2048,256,0,stream>>>(out, fb, c16, histlo);
    k_scan16<<<4,256,0,stream>>>(histlo, c16, r16, osv);

    // --- thresholds + mask (in-place on d_out) ---
    k_finalize<<<1,64,0,stream>>>(osv, gs, cw, lov, hiv);
    k_mask<<<NPIX/256,256,0,stream>>>(out, fb, lov, hiv, out);
}